// Round 3
// baseline (171.511 us; speedup 1.0000x reference)
//
#include <hip/hip_runtime.h>

// Problem constants: B=8, E=512, L=4096, D=256, fp32 in/out.
#define B_N 8
#define E_N 512
#define L_N 4096
#define D_N 256

#define SPLITK 8
#define KC_LEN (L_N / SPLITK)   // 512
#define KC_ITERS (KC_LEN / 64)  // 8

typedef __attribute__((ext_vector_type(8))) short short8;   // 8 bf16 (MFMA frag / 16B)
typedef __attribute__((ext_vector_type(4))) short short4v;  // 4 bf16 (8B)
typedef __attribute__((ext_vector_type(4))) float f32x4;

typedef const __attribute__((address_space(1))) void* gptr_t;
typedef __attribute__((address_space(3))) void* lptr_t;

__device__ __forceinline__ unsigned short f2bf(float f) {
    unsigned u = __float_as_uint(f);
    u += 0x7fffu + ((u >> 16) & 1u);
    return (unsigned short)(u >> 16);
}

#define LDT 72   // A-tile LDS leading dim (shorts): 16B-aligned b128 frags, conflict-free

// ---- Pre-pass: doc [B,L,D] fp32 -> docT [B,D,L] bf16, chunk-swizzled ----
// Within each 64-k tile of row d, the logical 8-elem chunk c lives at c ^ (d&7),
// so the main kernel's global_load_lds (lds = base + lane*16, unpadded) yields
// conflict-free-enough (2-way) MFMA frag reads.
__global__ __launch_bounds__(256)
void transpose_doc(const float* __restrict__ doc, unsigned short* __restrict__ docT)
{
    __shared__ float T[64 * 73];   // T[d][l], pad 73 -> 2-way max on both sides
    const int bb = blockIdx.z;
    const int d0 = blockIdx.y * 64;
    const int l0 = blockIdx.x * 64;

    const int t  = threadIdx.x;
    const int lr = t >> 4, c4 = t & 15;

    #pragma unroll
    for (int r = 0; r < 4; ++r) {
        const int l = lr + r * 16;
        f32x4 v = *(const f32x4*)(doc + ((size_t)bb * L_N + l0 + l) * D_N + d0 + c4 * 4);
        #pragma unroll
        for (int j = 0; j < 4; ++j)
            T[(c4 * 4 + j) * 73 + l] = v[j];
    }
    __syncthreads();

    const int dl = t >> 3, lc = t & 7;
    #pragma unroll
    for (int h = 0; h < 2; ++h) {
        const int d = dl + h * 32;
        short8 w;
        #pragma unroll
        for (int j = 0; j < 8; ++j)
            w[j] = (short)f2bf(T[d * 73 + lc * 8 + j]);
        const size_t base = ((size_t)bb * D_N + d0 + d) * L_N + l0;
        *(short8*)(docT + base + ((lc ^ (d & 7)) * 8)) = w;
    }
}

// ---- Main GEMM: out[b,e,d] += (map[b,e,kc]·docT[b,d,kc]) * invLen ----
__global__ __launch_bounds__(256)
void mp_gemm(const unsigned short* __restrict__ docT,  // [B,D,L] bf16 swizzled
             const float* __restrict__ map,            // [B,E,L] fp32
             const float* __restrict__ lens,
             float* __restrict__ out)                  // [B,E,D] pre-zeroed
{
    __shared__ unsigned short As[64 * LDT];      // As[m][k] bf16, padded
    __shared__ unsigned short Bs[2 * 64 * 64];   // Bs[buf][n][k] bf16, UNPADDED (async dst)
    __shared__ float invLen[64];

    const int b   = blockIdx.y;
    const int e0  = (blockIdx.x >> 2) * 64;
    const int d0  = (blockIdx.x & 3) * 64;
    const int kc0 = blockIdx.z * KC_LEN;

    const unsigned short* docTB = docT + (size_t)(b * D_N + d0) * L_N;
    const float* mapB = map + (size_t)b * E_N * L_N;
    float*       outB = out + (size_t)b * E_N * D_N;

    const int tid  = threadIdx.x;
    const int lane = tid & 63;
    const int wave = tid >> 6;

    if (tid < 64) invLen[tid] = 1.0f / lens[(size_t)b * E_N + e0 + tid];

    const int aRow0 = tid >> 4;
    const int aCol4 = tid & 15;
    const int bRow  = lane >> 3;   // row within 8-row async group
    const int bChk  = lane & 7;    // 16B chunk within row

    f32x4 ar[4];

    // preload tile 0: A -> regs, B -> Bs[0] async
    {
        #pragma unroll
        for (int r = 0; r < 4; ++r)
            ar[r] = *(const f32x4*)(mapB + (size_t)(e0 + aRow0 + r * 16) * L_N + kc0 + aCol4 * 4);
        #pragma unroll
        for (int i = 0; i < 2; ++i) {
            const int r0 = wave * 16 + i * 8;
            const unsigned short* src = docTB + (size_t)(r0 + bRow) * L_N + kc0 + bChk * 8;
            __builtin_amdgcn_global_load_lds((gptr_t)(const void*)src,
                                             (lptr_t)(void*)&Bs[r0 * 64], 16, 0, 0);
        }
    }

    const int wm = wave >> 1, wn = wave & 1;
    const int fm = lane & 15, q = lane >> 4;

    f32x4 acc[2][2] = {};
    int cur = 0;

    for (int it = 0; it < KC_ITERS; ++it) {
        if (it) __syncthreads();   // frag reads of it-1 done -> As rewrite safe

        // A regs -> LDS (fp32->bf16)
        #pragma unroll
        for (int r = 0; r < 4; ++r) {
            short4v w;
            w[0] = (short)f2bf(ar[r][0]);
            w[1] = (short)f2bf(ar[r][1]);
            w[2] = (short)f2bf(ar[r][2]);
            w[3] = (short)f2bf(ar[r][3]);
            *(short4v*)&As[(aRow0 + r * 16) * LDT + aCol4 * 4] = w;
        }
        __syncthreads();           // As visible; Bs[cur] async loads drained here

        // prefetch tile it+1 (A->regs, B->Bs[cur^1] async; in flight across compute)
        if (it + 1 < KC_ITERS) {
            const int k0 = kc0 + (it + 1) * 64;
            #pragma unroll
            for (int r = 0; r < 4; ++r)
                ar[r] = *(const f32x4*)(mapB + (size_t)(e0 + aRow0 + r * 16) * L_N + k0 + aCol4 * 4);
            const int nxt = cur ^ 1;
            #pragma unroll
            for (int i = 0; i < 2; ++i) {
                const int r0 = wave * 16 + i * 8;
                const unsigned short* src = docTB + (size_t)(r0 + bRow) * L_N + k0 + bChk * 8;
                __builtin_amdgcn_global_load_lds((gptr_t)(const void*)src,
                                                 (lptr_t)(void*)&Bs[nxt * 4096 + r0 * 64], 16, 0, 0);
            }
        }

        // compute 64x64x64 tile
        const unsigned short* Bc = &Bs[cur * 4096];
        #pragma unroll
        for (int kk = 0; kk < 2; ++kk) {
            short8 af[2], bf[2];
            #pragma unroll
            for (int mi = 0; mi < 2; ++mi)
                af[mi] = *(const short8*)&As[(wm * 32 + mi * 16 + fm) * LDT + kk * 32 + q * 8];
            #pragma unroll
            for (int ni = 0; ni < 2; ++ni) {
                const int r = wn * 32 + ni * 16 + fm;
                const int c = (kk * 4 + q) ^ (fm & 7);   // un-swizzle
                bf[ni] = *(const short8*)&Bc[r * 64 + c * 8];
            }
            #pragma unroll
            for (int mi = 0; mi < 2; ++mi)
                #pragma unroll
                for (int ni = 0; ni < 2; ++ni)
                    acc[mi][ni] = __builtin_amdgcn_mfma_f32_16x16x32_bf16(
                        af[mi], bf[ni], acc[mi][ni], 0, 0, 0);
        }
        cur ^= 1;
    }

    // epilogue: C/D layout col=lane&15, row=(lane>>4)*4+i; scale + atomic accumulate
    #pragma unroll
    for (int mi = 0; mi < 2; ++mi) {
        const int rLoc = wm * 32 + mi * 16 + q * 4;
        #pragma unroll
        for (int ni = 0; ni < 2; ++ni) {
            const int c = d0 + wn * 32 + ni * 16 + fm;
            #pragma unroll
            for (int i = 0; i < 4; ++i) {
                const int rr = rLoc + i;
                atomicAdd(&outB[(size_t)(e0 + rr) * D_N + c], acc[mi][ni][i] * invLen[rr]);
            }
        }
    }
}

// ---- Fallback (ws too small): round-2 kernel, register transpose ----
__global__ __launch_bounds__(256)
void mp_gemm_fb(const float* __restrict__ doc, const float* __restrict__ map,
                const float* __restrict__ lens, float* __restrict__ out)
{
    __shared__ unsigned short As[64 * LDT];
    __shared__ unsigned short Bs2[64 * LDT];
    __shared__ float invLen[64];

    const int b = blockIdx.y;
    const int e0 = (blockIdx.x >> 2) * 64;
    const int d0 = (blockIdx.x & 3) * 64;
    const int kc0 = blockIdx.z * KC_LEN;

    const float* docB = doc + (size_t)b * L_N * D_N;
    const float* mapB = map + (size_t)b * E_N * L_N;
    float*       outB = out + (size_t)b * E_N * D_N;

    const int tid = threadIdx.x, lane = tid & 63, wave = tid >> 6;
    if (tid < 64) invLen[tid] = 1.0f / lens[(size_t)b * E_N + e0 + tid];

    const int aRow0 = tid >> 4, aCol4 = tid & 15;
    const int nb = tid & 15, kb = tid >> 4;

    f32x4 ar[4], br[4];
    {
        #pragma unroll
        for (int r = 0; r < 4; ++r)
            ar[r] = *(const f32x4*)(mapB + (size_t)(e0 + aRow0 + r * 16) * L_N + kc0 + aCol4 * 4);
        #pragma unroll
        for (int i = 0; i < 4; ++i)
            br[i] = *(const f32x4*)(docB + (size_t)(kc0 + kb * 4 + i) * D_N + d0 + nb * 4);
    }

    const int wm = wave >> 1, wn = wave & 1, fm = lane & 15, q = lane >> 4;
    f32x4 acc[2][2] = {};

    for (int it = 0; it < KC_ITERS; ++it) {
        if (it) __syncthreads();
        #pragma unroll
        for (int r = 0; r < 4; ++r) {
            short4v w;
            w[0] = (short)f2bf(ar[r][0]); w[1] = (short)f2bf(ar[r][1]);
            w[2] = (short)f2bf(ar[r][2]); w[3] = (short)f2bf(ar[r][3]);
            *(short4v*)&As[(aRow0 + r * 16) * LDT + aCol4 * 4] = w;
        }
        #pragma unroll
        for (int j = 0; j < 4; ++j) {
            short4v w;
            w[0] = (short)f2bf(br[0][j]); w[1] = (short)f2bf(br[1][j]);
            w[2] = (short)f2bf(br[2][j]); w[3] = (short)f2bf(br[3][j]);
            *(short4v*)&Bs2[(nb * 4 + j) * LDT + kb * 4] = w;
        }
        __syncthreads();
        if (it + 1 < KC_ITERS) {
            const int k0 = kc0 + (it + 1) * 64;
            #pragma unroll
            for (int r = 0; r < 4; ++r)
                ar[r] = *(const f32x4*)(mapB + (size_t)(e0 + aRow0 + r * 16) * L_N + k0 + aCol4 * 4);
            #pragma unroll
            for (int i = 0; i < 4; ++i)
                br[i] = *(const f32x4*)(docB + (size_t)(k0 + kb * 4 + i) * D_N + d0 + nb * 4);
        }
        #pragma unroll
        for (int kk = 0; kk < 2; ++kk) {
            short8 af[2], bf[2];
            #pragma unroll
            for (int mi = 0; mi < 2; ++mi)
                af[mi] = *(const short8*)&As[(wm * 32 + mi * 16 + fm) * LDT + kk * 32 + q * 8];
            #pragma unroll
            for (int ni = 0; ni < 2; ++ni)
                bf[ni] = *(const short8*)&Bs2[(wn * 32 + ni * 16 + fm) * LDT + kk * 32 + q * 8];
            #pragma unroll
            for (int mi = 0; mi < 2; ++mi)
                #pragma unroll
                for (int ni = 0; ni < 2; ++ni)
                    acc[mi][ni] = __builtin_amdgcn_mfma_f32_16x16x32_bf16(
                        af[mi], bf[ni], acc[mi][ni], 0, 0, 0);
        }
    }
    #pragma unroll
    for (int mi = 0; mi < 2; ++mi) {
        const int rLoc = wm * 32 + mi * 16 + q * 4;
        #pragma unroll
        for (int ni = 0; ni < 2; ++ni) {
            const int c = d0 + wn * 32 + ni * 16 + fm;
            #pragma unroll
            for (int i = 0; i < 4; ++i)
                atomicAdd(&outB[(size_t)(e0 + rLoc + i) * D_N + c], acc[mi][ni][i] * invLen[rLoc + i]);
        }
    }
}

extern "C" void kernel_launch(void* const* d_in, const int* in_sizes, int n_in,
                              void* d_out, int out_size, void* d_ws, size_t ws_size,
                              hipStream_t stream) {
    const float* doc  = (const float*)d_in[0];
    const float* map  = (const float*)d_in[1];
    const float* lens = (const float*)d_in[2];
    float* out = (float*)d_out;

    hipMemsetAsync(out, 0, (size_t)out_size * sizeof(float), stream);

    const size_t need = (size_t)B_N * D_N * L_N * sizeof(unsigned short); // 16.8 MB
    if (ws_size >= need) {
        unsigned short* docT = (unsigned short*)d_ws;
        transpose_doc<<<dim3(L_N / 64, D_N / 64, B_N), 256, 0, stream>>>(doc, docT);
        mp_gemm<<<dim3(32, 8, SPLITK), 256, 0, stream>>>(docT, map, lens, out);
    } else {
        mp_gemm_fb<<<dim3(32, 8, SPLITK), 256, 0, stream>>>(doc, map, lens, out);
    }
}

// Round 5
// 165.731 us; speedup vs baseline: 1.0349x; 1.0349x over previous
//
#include <hip/hip_runtime.h>

// Problem: out[b,e,d] = sum_l map[b,e,l]*doc[b,l,d] / lens[b,e]
// B=8, E=512, L=4096, D=256, fp32.
#define B_N 8
#define E_N 512
#define L_N 4096
#define D_N 256

#define SK 8               // split-K chunks
#define KC (L_N / SK)      // 512 per block
#define BK 32              // K per iteration
#define ITERS (KC / BK)    // 16

typedef __attribute__((ext_vector_type(8)))  short short8;   // 8 bf16 (MFMA A/B frag)
typedef __attribute__((ext_vector_type(16))) float f32x16;   // 32x32 MFMA acc
typedef __attribute__((ext_vector_type(4)))  float f32x4;

typedef const __attribute__((address_space(1))) void* gptr_t;
typedef __attribute__((address_space(3))) void* lptr_t;

__device__ __forceinline__ unsigned short f2bf(float f) {
    unsigned u = __float_as_uint(f);
    u += 0x7fffu + ((u >> 16) & 1u);
    return (unsigned short)(u >> 16);
}

#define LDA 72   // As row stride (shorts): 16B-aligned, frag reads & writes at 8-phase min

__global__ __launch_bounds__(256)
void mp_gemm(const float* __restrict__ doc,   // [B,L,D]
             const float* __restrict__ map,   // [B,E,L]
             const float* __restrict__ lens,  // [B,E]
             float* __restrict__ out)         // [B,E,D] pre-zeroed, atomic accumulate
{
    __shared__ unsigned short As[64 * LDA];   // bf16 [64 e][32 k], padded
    __shared__ float Bs[2][BK][D_N];          // fp32 [32 k][256 d], double-buffered (async dst)
    __shared__ float invLen[64];

    const int e0  = blockIdx.x * 64;
    const int b   = blockIdx.y;
    const int kc0 = blockIdx.z * KC;

    const float* docB = doc + (size_t)b * L_N * D_N;
    const float* mapB = map + (size_t)b * E_N * L_N;
    float*       outB = out + (size_t)b * E_N * D_N;

    const int tid = threadIdx.x, lane = tid & 63, wave = tid >> 6;
    if (tid < 64) invLen[tid] = 1.0f / lens[(size_t)b * E_N + e0 + tid];

    // A staging: thread t -> row ar=t>>2, k-offset ka=(t&3)*8 (32B contiguous global read)
    const int ar = tid >> 2;
    const int ka = (tid & 3) * 8;

    // fragment coords (32x32x16): A[m][k] m=lane&31,k=(lane>>5)*8+j ; B[k][n] n=lane&31
    const int fm = lane & 31;
    const int fh = lane >> 5;
    const int dw = wave * 64;   // wave's 64-wide d-slice of the 256-wide tile

    f32x4 a0, a1;

    // ---- preload tile 0: A -> regs, B rows -> Bs[0] via async global_load_lds ----
    // NOTE: global src of global_load_lds is PER-LANE (lane*16B); LDS dst is
    // wave-uniform base + lane*16. (R4 bug: uniform src -> garbage rows.)
    {
        const float* ap = mapB + (size_t)(e0 + ar) * L_N + kc0 + ka;
        a0 = *(const f32x4*)ap;
        a1 = *(const f32x4*)(ap + 4);
        #pragma unroll
        for (int i = 0; i < 8; ++i) {
            const int kr = wave * 8 + i;   // each wave-instr stages one 1KB row
            __builtin_amdgcn_global_load_lds(
                (gptr_t)(const void*)(docB + (size_t)(kc0 + kr) * D_N + lane * 4),
                (lptr_t)(void*)&Bs[0][kr][0], 16, 0, 0);
        }
    }

    f32x16 acc[2][2] = {};   // [mi][ni] 32x32 tiles: rows mi*32, cols dw+ni*32
    int cur = 0;

    for (int it = 0; it < ITERS; ++it) {
        if (it) __syncthreads();   // prev compute done; drains async for Bs[cur]

        // A regs -> As bf16 (one 16B write per thread)
        {
            short8 w;
            w[0] = (short)f2bf(a0[0]); w[1] = (short)f2bf(a0[1]);
            w[2] = (short)f2bf(a0[2]); w[3] = (short)f2bf(a0[3]);
            w[4] = (short)f2bf(a1[0]); w[5] = (short)f2bf(a1[1]);
            w[6] = (short)f2bf(a1[2]); w[7] = (short)f2bf(a1[3]);
            *(short8*)&As[ar * LDA + ka] = w;
        }
        __syncthreads();           // As visible; Bs[cur] fully landed

        // prefetch tile it+1: A -> regs, B -> Bs[cur^1] async (in flight across compute)
        if (it + 1 < ITERS) {
            const int k0 = kc0 + (it + 1) * BK;
            const float* ap = mapB + (size_t)(e0 + ar) * L_N + k0 + ka;
            a0 = *(const f32x4*)ap;
            a1 = *(const f32x4*)(ap + 4);
            const int nxt = cur ^ 1;
            #pragma unroll
            for (int i = 0; i < 8; ++i) {
                const int kr = wave * 8 + i;
                __builtin_amdgcn_global_load_lds(
                    (gptr_t)(const void*)(docB + (size_t)(k0 + kr) * D_N + lane * 4),
                    (lptr_t)(void*)&Bs[nxt][kr][0], 16, 0, 0);
            }
        }

        // ---- compute 64x256 x BK=32 tile: 2 K-steps of 16 ----
        const float* Bp = &Bs[cur][0][0];
        #pragma unroll
        for (int kk = 0; kk < 2; ++kk) {
            short8 af[2];
            #pragma unroll
            for (int mi = 0; mi < 2; ++mi)
                af[mi] = *(const short8*)&As[(mi * 32 + fm) * LDA + kk * 16 + fh * 8];

            short8 bf2[2];
            #pragma unroll
            for (int ni = 0; ni < 2; ++ni) {
                // column gather: 8 x ds_read_b32, bank = d%32 = fm -> 2-way (free)
                const float* col = Bp + (size_t)(kk * 16 + fh * 8) * D_N + dw + ni * 32 + fm;
                short8 w;
                #pragma unroll
                for (int j = 0; j < 8; ++j)
                    w[j] = (short)f2bf(col[(size_t)j * D_N]);
                bf2[ni] = w;
            }

            #pragma unroll
            for (int mi = 0; mi < 2; ++mi)
                #pragma unroll
                for (int ni = 0; ni < 2; ++ni)
                    acc[mi][ni] = __builtin_amdgcn_mfma_f32_32x32x16_bf16(
                        af[mi], bf2[ni], acc[mi][ni], 0, 0, 0);
        }
        cur ^= 1;
    }

    // ---- epilogue: 32x32 C/D layout col=lane&31, row=(r&3)+8*(r>>2)+4*(lane>>5) ----
    #pragma unroll
    for (int mi = 0; mi < 2; ++mi) {
        #pragma unroll
        for (int ni = 0; ni < 2; ++ni) {
            const int col = dw + ni * 32 + fm;
            #pragma unroll
            for (int r = 0; r < 16; ++r) {
                const int row = mi * 32 + (r & 3) + 8 * (r >> 2) + 4 * fh;
                atomicAdd(&outB[(size_t)(e0 + row) * D_N + col],
                          acc[mi][ni][r] * invLen[row]);
            }
        }
    }
}

extern "C" void kernel_launch(void* const* d_in, const int* in_sizes, int n_in,
                              void* d_out, int out_size, void* d_ws, size_t ws_size,
                              hipStream_t stream) {
    const float* doc  = (const float*)d_in[0];
    const float* map  = (const float*)d_in[1];
    const float* lens = (const float*)d_in[2];
    float* out = (float*)d_out;

    // d_out poisoned 0xAA every call; split-K accumulates atomically.
    hipMemsetAsync(out, 0, (size_t)out_size * sizeof(float), stream);

    dim3 grid(E_N / 64, B_N, SK);   // 8 x 8 x 8 = 512 blocks, 2/CU (LDS 75 KB)
    mp_gemm<<<grid, 256, 0, stream>>>(doc, map, lens, out);
}